// Round 16
// baseline (231.910 us; speedup 1.0000x reference)
//
#include <hip/hip_runtime.h>
#include <cstdint>
#include <cstddef>

typedef unsigned short u16;
typedef unsigned int u32;
typedef float f32x4 __attribute__((ext_vector_type(4)));
typedef short short8 __attribute__((ext_vector_type(8)));
typedef u32 u32x2 __attribute__((ext_vector_type(2)));

#define HW 196
#define DIM 1024
#define HD 64
#define SP 208
#define SPV 224
#define NBH 1024

__device__ __forceinline__ float bf2f(u16 x){
  union { u32 u; float f; } c; c.u = ((u32)x) << 16; return c.f;
}
__device__ __forceinline__ u16 f2bf(float f){
  union { float f; u32 u; } c; c.f = f;
  return (u16)((c.u + 0x7fffu + ((c.u >> 16) & 1u)) >> 16);
}
__device__ __forceinline__ u32 cvtpk_bf16(float lo, float hi){
  u32 r;
  asm("v_cvt_pk_bf16_f32 %0, %1, %2" : "=v"(r) : "v"(lo), "v"(hi));
  return r;
}
#define LGKM_FENCE() do { \
    asm volatile("s_waitcnt lgkmcnt(0)" ::: "memory"); \
    __builtin_amdgcn_sched_barrier(0); \
  } while (0)
// DS-order fence that still lets VMEM/VALU cross (mask = all but DS*)
#define DS_FENCE() do { \
    asm volatile("s_waitcnt lgkmcnt(0)" ::: "memory"); \
    __builtin_amdgcn_sched_barrier(0x7F); \
  } while (0)
#define WAITV4() asm volatile("s_waitcnt vmcnt(4)" ::: "memory")
#define BAR() __builtin_amdgcn_s_barrier()

typedef __attribute__((address_space(3))) void lds_void_t;
typedef __attribute__((address_space(1))) const void glb_void_t;
__device__ __forceinline__ void gload_lds16(const void* g, void* l){
  __builtin_amdgcn_global_load_lds((glb_void_t*)g, (lds_void_t*)l, 16, 0, 0);
}

// ---- merged prep: x->bf16 | qkv_w^T->bf16 | proj_w^T->bf16 | rel tables ----
// blocks [0,6272): xcvt; [6272,9344): wT qkv; [9344,10368): wT proj; [10368]: rprep
__global__ __launch_bounds__(256) void k_prep(const float* __restrict__ x,
    u16* __restrict__ xb,
    const float* __restrict__ qkv_w, u16* __restrict__ wqkvT,
    const float* __restrict__ proj_w, u16* __restrict__ wprojT,
    const float* __restrict__ rph, const float* __restrict__ rpw,
    u16* __restrict__ rphb, u16* __restrict__ rpwb)
{
  __shared__ float t[32][33];
  int blk = blockIdx.x;
  if (blk < 6272){
    int i = blk * 256 + threadIdx.x;
    const f32x4* p = (const f32x4*)(x + (size_t)i * 8);
    f32x4 v0 = p[0], v1 = p[1];
    short8 tt;
    #pragma unroll
    for (int e = 0; e < 4; ++e){
      tt[e]   = (short)f2bf(v0[e]);
      tt[4+e] = (short)f2bf(v1[e]);
    }
    *(short8*)(xb + (size_t)i * 8) = tt;
  } else if (blk < 10368){
    const float* w; u16* wT; int K = 1024, N; int idx;
    if (blk < 9344){ w = qkv_w; wT = wqkvT; N = 3072; idx = blk - 6272; }
    else           { w = proj_w; wT = wprojT; N = 1024; idx = blk - 9344; }
    int nb = N >> 5;
    int n0 = (idx % nb) * 32, k0 = (idx / nb) * 32;
    int c = threadIdx.x & 31, rr = threadIdx.x >> 5;
    #pragma unroll
    for (int i = 0; i < 4; ++i){
      int r = rr + i*8;
      t[r][c] = w[(size_t)(k0 + r) * N + n0 + c];
    }
    __syncthreads();
    #pragma unroll
    for (int i = 0; i < 4; ++i){
      int r = rr + i*8;
      wT[(size_t)(n0 + r) * K + k0 + c] = f2bf(t[c][r]);
    }
  } else {
    int r = threadIdx.x >> 3, cc = (threadIdx.x & 7) * 8;
    #pragma unroll
    for (int tsel = 0; tsel < 2; ++tsel){
      const float* src = tsel ? rpw : rph;
      u16* dst = tsel ? rpwb : rphb;
      short8 v;
      #pragma unroll
      for (int e = 0; e < 8; ++e)
        v[e] = (r < 27) ? (short)f2bf(src[(size_t)r * 64 + cc + e]) : (short)0;
      *(short8*)(dst + (size_t)r * 64 + cc) = v;
    }
  }
}

// ================= 256x256 8-phase GEMM (T2+T3+T4+T5) =================
// MEASURED-BEST schedule (R8/R12/R15: 116.3-116.7us QKV). Structure
// experiments all regressed: BK32-3bar 123.7 (R10), BK32-1sync 128.2 (R11),
// 9-slot ring L=7 136.1 (R14), L=9 broken (R13). K-LOOP IS FROZEN.
// Counted vmcnt(4) waits sit BEFORE the barrier preceding the dependent
// ds_reads (phase1 guards {A1,B1}(t); phase3 guards {A0,B0}(t+1)); loads
// never drain below 4 outstanding. launch_bounds(512,2): natural VGPR ~100,
// no spill (R9: (512,4) caps VGPR at 64, spills acc -> 5-10x regression).
// MFMA operand-swapped (C^T frags). MODE 0: merged QKV epilogue, runtime
// branch per 1024-aligned column third. MODE 1: f32 out + bias.
template<int MODE>
__global__ __launch_bounds__(512, 2) void k_g256(const u16* __restrict__ Ab,
    const u16* __restrict__ Bt, const float* __restrict__ bias,
    u16* __restrict__ qg, u16* __restrict__ kg, u16* __restrict__ vTg,
    float* __restrict__ outf, int K, int N, int ntm, int ntn)
{
  extern __shared__ __align__(16) u16 smem[];   // [d][ab][ks][256][32] = 128 KiB
  const int tid = threadIdx.x;
  const int lane = tid & 63, wv = tid >> 6;
  const int wr = wv >> 2, wc = wv & 3;
  const int l16 = lane & 15, lk = lane >> 4;

  const int nwg = ntm * ntn;
  int bid = blockIdx.x;
  int q8 = nwg >> 3, r8 = nwg & 7;
  int xcd = bid & 7, loc = bid >> 3;
  int wgid = (xcd < r8 ? xcd*(q8+1) : r8*(q8+1) + (xcd - r8)*q8) + loc;
  int gsz = 8 * ntn;
  int g = wgid / gsz, rem = wgid - g * gsz;
  int gm = ntm - g * 8; if (gm > 8) gm = 8;
  int ry = g * 8 + rem % gm;
  int cy = rem / gm;
  const size_t m0 = (size_t)ry * 256;
  const size_t n0 = (size_t)cy * 256;
  const int nk = K >> 6;

  auto off = [&](int d, int ab, int ks){ return ((d*2 + ab)*2 + ks) * 8192; };

  auto stageH = [&](int d, int ab, int ks, int tile){
    const u16* src = ab ? Bt : Ab;
    size_t rb = ab ? n0 : m0;
    int c = (lane & 3) ^ ((lane >> 3) & 3);     // inverse read-swizzle on source
    #pragma unroll
    for (int i = 0; i < 2; ++i){
      int rh = 32*wv + 16*i + (lane >> 2);
      gload_lds16(src + (rb + rh) * (size_t)K + tile*64 + ks*32 + c*8,
                  smem + off(d, ab, ks) + (32*wv + 16*i) * 32);
    }
  };
  auto ldA = [&](short8* a, int d, int ks, int h){
    #pragma unroll
    for (int m2 = 0; m2 < 4; ++m2){
      int r = wr*128 + h*64 + m2*16 + l16;
      a[m2] = *(const short8*)(smem + off(d,0,ks) + r*32 + ((lk ^ ((r>>1)&3)) << 3));
    }
  };
  auto ldB = [&](short8* b, int d, int ks){
    #pragma unroll
    for (int ni = 0; ni < 4; ++ni){
      int r = wc*64 + ni*16 + l16;
      b[ni] = *(const short8*)(smem + off(d,1,ks) + r*32 + ((lk ^ ((r>>1)&3)) << 3));
    }
  };

  f32x4 acc[8][4] = {};
  auto mm = [&](int h, short8* a, short8* b){
    __builtin_amdgcn_s_setprio(1);
    #pragma unroll
    for (int m2 = 0; m2 < 4; ++m2)
      #pragma unroll
      for (int ni = 0; ni < 4; ++ni)
        acc[h*4+m2][ni] = __builtin_amdgcn_mfma_f32_16x16x32_bf16(b[ni], a[m2], acc[h*4+m2][ni], 0, 0, 0);
    __builtin_amdgcn_s_setprio(0);
  };

  // prologue: tile 0; guarantee {A0,B0}(0) before the loop's first ds_reads
  stageH(0, 0, 0, 0); stageH(0, 1, 0, 0); stageH(0, 0, 1, 0); stageH(0, 1, 1, 0);
  WAITV4(); BAR();

  #pragma unroll 1
  for (int kt = 0; kt < nk; ++kt){
    const int d = kt & 1, dn = d ^ 1;
    const int tn = (kt + 1 < nk) ? kt + 1 : nk - 1;  // redundant restage keeps wait counts valid
    short8 a[4], b0[4], b1[4];
    // phase 0: (h0, ks0) — {A0,B0}(kt) guaranteed by prev phase-3 wait + BAR
    ldA(a, d, 0, 0); ldB(b0, d, 0);
    stageH(dn, 0, 0, tn);
    BAR(); LGKM_FENCE();
    mm(0, a, b0);
    BAR();
    // phase 1: (h1, ks0) — reuse b0; wait completes {A1,B1}(kt) for phase 2
    ldA(a, d, 0, 1);
    stageH(dn, 1, 0, tn);
    WAITV4();
    BAR(); LGKM_FENCE();
    mm(1, a, b0);
    BAR();
    // phase 2: (h0, ks1)
    ldA(a, d, 1, 0); ldB(b1, d, 1);
    stageH(dn, 0, 1, tn);
    BAR(); LGKM_FENCE();
    mm(0, a, b1);
    BAR();
    // phase 3: (h1, ks1) — wait completes {A0,B0}(kt+1) for next phase 0
    ldA(a, d, 1, 1);
    stageH(dn, 1, 1, tn);
    WAITV4();
    BAR(); LGKM_FENCE();
    mm(1, a, b1);
    BAR();
  }

  const int rowb = (int)m0 + wr*128;
  const int colb = (int)n0 + wc*64;
  if constexpr (MODE == 1){
    #pragma unroll
    for (int mi = 0; mi < 8; ++mi){
      int r = rowb + mi*16 + l16;
      float* orow = outf + (size_t)r * N;
      #pragma unroll
      for (int ni = 0; ni < 4; ++ni){
        int c0 = colb + ni*16 + lk*4;
        f32x4 bz = *(const f32x4*)(bias + c0);
        f32x4 v = acc[mi][ni] + bz;
        *(f32x4*)(orow + c0) = v;
      }
    }
  } else {
    const int t3 = colb >> 10;
    if (t3 < 2){
      u16* dst0 = (t3 == 0) ? qg : kg;
      const float sc = (t3 == 0) ? 1.0f : 0.125f;   // fold qk-scale into K
      #pragma unroll
      for (int mi = 0; mi < 8; ++mi){
        int r = rowb + mi*16 + l16;
        int b = r / 196, n = r - b * 196;
        #pragma unroll
        for (int ni = 0; ni < 4; ++ni){
          int rr2 = ((colb & 1023) + ni*16);
          int hh = rr2 >> 6, ccb = (rr2 & 63) + lk*4;
          const float* bz = bias + colb + ni*16 + lk*4;
          u32 w0 = cvtpk_bf16((acc[mi][ni][0] + bz[0])*sc, (acc[mi][ni][1] + bz[1])*sc);
          u32 w1 = cvtpk_bf16((acc[mi][ni][2] + bz[2])*sc, (acc[mi][ni][3] + bz[3])*sc);
          u32* dst = (u32*)(dst0 + ((size_t)(hh*64 + b) * SP + n) * HD + ccb);
          dst[0] = w0; dst[1] = w1;
        }
      }
    } else {
      // v third (SW layout): per frag 4 scalar u16 stores, stride SPV elems.
      // Pads n in [196,224) are never written: attn multiplies them by P==0
      // exactly, and 0xAA / stale bf16 garbage is finite -> no memset needed.
      #pragma unroll
      for (int mi = 0; mi < 8; ++mi){
        int r = rowb + mi*16 + l16;
        int b = r / 196, n = r - b * 196;
        #pragma unroll
        for (int ni = 0; ni < 4; ++ni){
          int col0 = colb + ni*16 + lk*4;
          f32x4 bz = *(const f32x4*)(bias + col0);
          int rem2 = col0 & 1023;
          int hh = rem2 >> 6, cc0 = rem2 & 63;
          u16* base = vTg + ((size_t)(hh*64 + b) * HD + cc0) * SPV + n;
          #pragma unroll
          for (int i = 0; i < 4; ++i)
            base[(size_t)i * SPV] = f2bf(acc[mi][ni][i] + bz[i]);
        }
      }
    }
  }
}

// ---- fused attention: one BLOCK per bh (13 waves); K/V staged once in LDS ----
// T14 async-STAGE: K/V global loads issued FIRST; rel-MFMA phase runs under
// their latency; ds_writes land just before the single __syncthreads.
#define KSTR 144
#define VSTR 464
#define PWB  7424
__global__ __launch_bounds__(832, 1) void k_attn(
    const u16* __restrict__ qg, const u16* __restrict__ kg, const u16* __restrict__ vTg,
    const u16* __restrict__ rphb, const u16* __restrict__ rpwb,
    u16* __restrict__ ao)
{
  extern __shared__ __align__(16) char asmem[];
  char* Klds = asmem;                    // 208 x 144B (128 used)
  char* Vlds = asmem + 29952;            // 64 x 464B (448 used)
  const int tid = threadIdx.x, lane = tid & 63, wvi = tid >> 6;  // 0..12
  const int l16 = lane & 15, lk = lane >> 4;
  char*  wbase = asmem + 59648 + wvi * PWB;
  float* relT  = (float*)wbase;          // [16][68] f32
  u32*   Pp    = (u32*)wbase;            // [16][116] u32 (alias; disjoint lifetime)

  const int bh = blockIdx.x;
  const int hh = bh >> 6, bb = bh & 63;
  const u16* qb = qg  + (size_t)bh * SP * HD;
  const u16* kb = kg  + (size_t)bh * SP * HD;
  const u16* vb = vTg + (size_t)bh * HD * SPV;

  // ---- T14 issue: K (2 chunks/thread, uniform) + V (2-3 chunks/thread) ----
  short8 kr0, kr1, vr0, vr1, vr2;
  const int kc0 = tid, kc1 = tid + 832;          // 1664 K-chunks total
  const int vc0 = tid, vc1 = tid + 832;          // 1792 V-chunks total
  const int vrow0 = vc0 / 28, vrow1 = vc1 / 28;
  kr0 = *(const short8*)((const char*)kb + (kc0 >> 3)*128 + ((kc0 & 7) << 4));
  kr1 = *(const short8*)((const char*)kb + (kc1 >> 3)*128 + ((kc1 & 7) << 4));
  vr0 = *(const short8*)((const char*)vb + vrow0*448 + ((vc0 - vrow0*28) << 4));
  vr1 = *(const short8*)((const char*)vb + vrow1*448 + ((vc1 - vrow1*28) << 4));
  const int vc2 = tid + 1664, vrow2 = vc2 / 28;
  if (tid < 128)
    vr2 = *(const short8*)((const char*)vb + vrow2*448 + ((vc2 - vrow2*28) << 4));

  const int mt = wvi;
  const short8 a0 = *(const short8*)(qb + (size_t)(mt*16 + l16) * HD + lk*8);
  const short8 a1 = *(const short8*)(qb + (size_t)(mt*16 + l16) * HD + 32 + lk*8);

  // rel tables via MFMA: lane(l16,lk) reg i = T[delta=dt*16+lk*4+i][q=l16]
  // (no Klds/Vlds dependency -> runs under the K/V load latency)
  {
    f32x4 z = {0.f,0.f,0.f,0.f};
    f32x4 racc[2][2] = {{z,z},{z,z}};
    #pragma unroll
    for (int dt = 0; dt < 2; ++dt){
      short8 h0 = *(const short8*)(rphb + (size_t)(dt*16 + l16) * 64 + lk*8);
      short8 h1 = *(const short8*)(rphb + (size_t)(dt*16 + l16) * 64 + 32 + lk*8);
      short8 w0 = *(const short8*)(rpwb + (size_t)(dt*16 + l16) * 64 + lk*8);
      short8 w1 = *(const short8*)(rpwb + (size_t)(dt*16 + l16) * 64 + 32 + lk*8);
      racc[0][dt] = __builtin_amdgcn_mfma_f32_16x16x32_bf16(h0, a0, racc[0][dt], 0, 0, 0);
      racc[0][dt] = __builtin_amdgcn_mfma_f32_16x16x32_bf16(h1, a1, racc[0][dt], 0, 0, 0);
      racc[1][dt] = __builtin_amdgcn_mfma_f32_16x16x32_bf16(w0, a0, racc[1][dt], 0, 0, 0);
      racc[1][dt] = __builtin_amdgcn_mfma_f32_16x16x32_bf16(w1, a1, racc[1][dt], 0, 0, 0);
    }
    #pragma unroll
    for (int t = 0; t < 2; ++t)
      #pragma unroll
      for (int dt = 0; dt < 2; ++dt)
        *(f32x4*)(relT + l16*68 + t*32 + dt*16 + lk*4) = racc[t][dt];
  }
  DS_FENCE();

  int qr = mt*16 + l16;
  int qrc = qr > HW-1 ? HW-1 : qr;
  int qh = qrc / 14, qw = qrc - 14*qh;
  const float* rrow = relT + l16*68;
  const int dh0 = qh + 13, dw0 = 32 + qw + 13;
  const int lk4 = lk*4;

  f32x4 sacc[13];
  #pragma unroll
  for (int nt = 0; nt < 13; ++nt){
    #pragma unroll
    for (int i = 0; i < 4; ++i){
      int k = nt*16 + lk4 + i;
      int kh = (k * 4682) >> 16;
      if (nt == 12 && kh > 13) kh = 13;
      int kw = k - kh*14;
      float bias = rrow[dh0 - kh] + rrow[dw0 - kw];
      sacc[nt][i] = (nt == 12 && lk != 0) ? -1e30f : bias;
    }
  }

  // ---- T14 land: ds_write K/V (vmcnt waits auto-inserted), then barrier ----
  *(short8*)(Klds + (kc0 >> 3)*KSTR + ((kc0 & 7) << 4)) = kr0;
  *(short8*)(Klds + (kc1 >> 3)*KSTR + ((kc1 & 7) << 4)) = kr1;
  *(short8*)(Vlds + vrow0*VSTR + ((vc0 - vrow0*28) << 4)) = vr0;
  *(short8*)(Vlds + vrow1*VSTR + ((vc1 - vrow1*28) << 4)) = vr1;
  if (tid < 128)
    *(short8*)(Vlds + vrow2*VSTR + ((vc2 - vrow2*28) << 4)) = vr2;
  __syncthreads();

  // QK^T swapped from K LDS (K pre-scaled by 0.125 at the GEMM epilogue)
  #pragma unroll
  for (int nt = 0; nt < 13; ++nt){
    int row = nt*16 + l16;
    short8 b0 = *(const short8*)(Klds + row*KSTR + lk*16);
    short8 b1 = *(const short8*)(Klds + row*KSTR + 64 + lk*16);
    sacc[nt] = __builtin_amdgcn_mfma_f32_16x16x32_bf16(b0, a0, sacc[nt], 0, 0, 0);
    sacc[nt] = __builtin_amdgcn_mfma_f32_16x16x32_bf16(b1, a1, sacc[nt], 0, 0, 0);
  }

  float m;
  {
    float t0[13];
    #pragma unroll
    for (int nt = 0; nt < 13; ++nt)
      t0[nt] = fmaxf(fmaxf(sacc[nt][0], sacc[nt][1]), fmaxf(sacc[nt][2], sacc[nt][3]));
    float a01 = fmaxf(t0[0], t0[1]),  a23 = fmaxf(t0[2], t0[3]);
    float a45 = fmaxf(t0[4], t0[5]),  a67 = fmaxf(t0[6], t0[7]);
    float a89 = fmaxf(t0[8], t0[9]),  aab = fmaxf(t0[10], t0[11]);
    m = fmaxf(fmaxf(fmaxf(a01, a23), fmaxf(a45, a67)), fmaxf(fmaxf(a89, aab), t0[12]));
  }
  m = fmaxf(m, __shfl_xor(m, 16, 64));
  m = fmaxf(m, __shfl_xor(m, 32, 64));
  float sum;
  {
    float s4[13];
    #pragma unroll
    for (int nt = 0; nt < 13; ++nt){
      #pragma unroll
      for (int i = 0; i < 4; ++i)
        sacc[nt][i] = __expf(sacc[nt][i] - m);
      s4[nt] = (sacc[nt][0] + sacc[nt][1]) + (sacc[nt][2] + sacc[nt][3]);
    }
    float b01 = s4[0]+s4[1], b23 = s4[2]+s4[3], b45 = s4[4]+s4[5];
    float b67 = s4[6]+s4[7], b89 = s4[8]+s4[9], bab = s4[10]+s4[11];
    sum = ((b01+b23) + (b45+b67)) + ((b89+bab) + s4[12]);
  }
  sum += __shfl_xor(sum, 16, 64);
  sum += __shfl_xor(sum, 32, 64);
  float inv = 1.0f / sum;

  DS_FENCE();
  u32* prow = Pp + l16*116;
  #pragma unroll
  for (int nt = 0; nt < 13; ++nt){
    u32x2 wpk;
    wpk[0] = cvtpk_bf16(sacc[nt][0], sacc[nt][1]);
    wpk[1] = cvtpk_bf16(sacc[nt][2], sacc[nt][3]);
    *(u32x2*)(prow + nt*8 + lk*2) = wpk;
  }
  { u32x2 zz = {0u, 0u}; *(u32x2*)(prow + 104 + lk*2) = zz; }
  DS_FENCE();

  f32x4 z = {0.f,0.f,0.f,0.f};
  f32x4 oacc[4] = {z,z,z,z};
  #pragma unroll
  for (int kt = 0; kt < 7; ++kt){
    short8 pa = *(const short8*)(prow + kt*16 + lk4);
    #pragma unroll
    for (int dt = 0; dt < 4; ++dt){
      short8 bv = *(const short8*)(Vlds + (dt*16 + l16)*VSTR + kt*64 + lk*16);
      oacc[dt] = __builtin_amdgcn_mfma_f32_16x16x32_bf16(bv, pa, oacc[dt], 0, 0, 0);
    }
  }
  int qrow = mt*16 + l16;
  if (qrow < HW){
    u16* orow = ao + ((size_t)bb * HW + qrow) * DIM + hh * HD;
    #pragma unroll
    for (int dt = 0; dt < 4; ++dt){
      u32 lo = cvtpk_bf16(oacc[dt][0]*inv, oacc[dt][1]*inv);
      u32 hi = cvtpk_bf16(oacc[dt][2]*inv, oacc[dt][3]*inv);
      u32* dst = (u32*)(orow + dt*16 + lk4);
      dst[0] = lo; dst[1] = hi;
    }
  }
}

extern "C" void kernel_launch(void* const* d_in, const int* in_sizes, int n_in,
                              void* d_out, int out_size, void* d_ws, size_t ws_size,
                              hipStream_t stream)
{
  const float* x      = (const float*)d_in[0];
  const float* qkv_w  = (const float*)d_in[1];
  const float* qkv_b  = (const float*)d_in[2];
  const float* proj_w = (const float*)d_in[3];
  const float* proj_b = (const float*)d_in[4];
  const float* rph    = (const float*)d_in[5];
  const float* rpw    = (const float*)d_in[6];
  float* out = (float*)d_out;
  char* ws = (char*)d_ws;

  size_t off = 0;
  auto alloc = [&](size_t b){ size_t r = off; off += (b + 255) & ~(size_t)255; return r; };
  u16* wqkvT = (u16*)(ws + alloc((size_t)3072*1024*2));
  u16* wprojT= (u16*)(ws + alloc((size_t)1024*1024*2));
  u16* qg    = (u16*)(ws + alloc((size_t)NBH*SP*HD*2));
  u16* kg    = (u16*)(ws + alloc((size_t)NBH*SP*HD*2));
  u16* vTg   = (u16*)(ws + alloc((size_t)NBH*HD*SPV*2));
  u16* rphb  = (u16*)(ws + alloc((size_t)32*64*2));
  u16* rpwb  = (u16*)(ws + alloc((size_t)32*64*2));
  u16* xb    = (u16*)(ws + alloc((size_t)12544*1024*2));
  u16* ao    = xb;   // disjoint lifetimes

  hipFuncSetAttribute((const void*)k_g256<0>, hipFuncAttributeMaxDynamicSharedMemorySize, 131072);
  hipFuncSetAttribute((const void*)k_g256<1>, hipFuncAttributeMaxDynamicSharedMemorySize, 131072);
  hipFuncSetAttribute((const void*)k_attn,    hipFuncAttributeMaxDynamicSharedMemorySize, 156160);

  k_prep<<<10369, 256, 0, stream>>>(x, xb, qkv_w, wqkvT, proj_w, wprojT,
                                    rph, rpw, rphb, rpwb);
  k_g256<0><<<49*12, 512, 131072, stream>>>(xb, wqkvT, qkv_b, qg, kg, vTg, nullptr,
                                            1024, 3072, 49, 12);
  k_attn<<<1024, 832, 156160, stream>>>(qg, kg, vTg, rphb, rpwb, ao);
  k_g256<1><<<49*4, 512, 131072, stream>>>(ao, wprojT, proj_b, nullptr, nullptr, nullptr, out,
                                           1024, 1024, 49, 4);
}

// Round 17
// 215.208 us; speedup vs baseline: 1.0776x; 1.0776x over previous
//
#include <hip/hip_runtime.h>
#include <cstdint>
#include <cstddef>

typedef unsigned short u16;
typedef unsigned int u32;
typedef float f32x4 __attribute__((ext_vector_type(4)));
typedef short short8 __attribute__((ext_vector_type(8)));
typedef u32 u32x2 __attribute__((ext_vector_type(2)));

#define HW 196
#define DIM 1024
#define HD 64
#define SP 208
#define SPV 224
#define NBH 1024

__device__ __forceinline__ float bf2f(u16 x){
  union { u32 u; float f; } c; c.u = ((u32)x) << 16; return c.f;
}
__device__ __forceinline__ u16 f2bf(float f){
  union { float f; u32 u; } c; c.f = f;
  return (u16)((c.u + 0x7fffu + ((c.u >> 16) & 1u)) >> 16);
}
__device__ __forceinline__ u32 cvtpk_bf16(float lo, float hi){
  u32 r;
  asm("v_cvt_pk_bf16_f32 %0, %1, %2" : "=v"(r) : "v"(lo), "v"(hi));
  return r;
}
#define LGKM_FENCE() do { \
    asm volatile("s_waitcnt lgkmcnt(0)" ::: "memory"); \
    __builtin_amdgcn_sched_barrier(0); \
  } while (0)
// DS-order fence that still lets VMEM/VALU cross (mask = all but DS*)
#define DS_FENCE() do { \
    asm volatile("s_waitcnt lgkmcnt(0)" ::: "memory"); \
    __builtin_amdgcn_sched_barrier(0x7F); \
  } while (0)
#define WAITV4() asm volatile("s_waitcnt vmcnt(4)" ::: "memory")
#define BAR() __builtin_amdgcn_s_barrier()

typedef __attribute__((address_space(3))) void lds_void_t;
typedef __attribute__((address_space(1))) const void glb_void_t;
__device__ __forceinline__ void gload_lds16(const void* g, void* l){
  __builtin_amdgcn_global_load_lds((glb_void_t*)g, (lds_void_t*)l, 16, 0, 0);
}

// ---- merged prep: x->bf16 | qkv_w^T->bf16 | proj_w^T->bf16 | rel tables ----
// blocks [0,6272): xcvt; [6272,9344): wT qkv; [9344,10368): wT proj; [10368]: rprep
__global__ __launch_bounds__(256) void k_prep(const float* __restrict__ x,
    u16* __restrict__ xb,
    const float* __restrict__ qkv_w, u16* __restrict__ wqkvT,
    const float* __restrict__ proj_w, u16* __restrict__ wprojT,
    const float* __restrict__ rph, const float* __restrict__ rpw,
    u16* __restrict__ rphb, u16* __restrict__ rpwb)
{
  __shared__ float t[32][33];
  int blk = blockIdx.x;
  if (blk < 6272){
    int i = blk * 256 + threadIdx.x;
    const f32x4* p = (const f32x4*)(x + (size_t)i * 8);
    f32x4 v0 = p[0], v1 = p[1];
    short8 tt;
    #pragma unroll
    for (int e = 0; e < 4; ++e){
      tt[e]   = (short)f2bf(v0[e]);
      tt[4+e] = (short)f2bf(v1[e]);
    }
    *(short8*)(xb + (size_t)i * 8) = tt;
  } else if (blk < 10368){
    const float* w; u16* wT; int K = 1024, N; int idx;
    if (blk < 9344){ w = qkv_w; wT = wqkvT; N = 3072; idx = blk - 6272; }
    else           { w = proj_w; wT = wprojT; N = 1024; idx = blk - 9344; }
    int nb = N >> 5;
    int n0 = (idx % nb) * 32, k0 = (idx / nb) * 32;
    int c = threadIdx.x & 31, rr = threadIdx.x >> 5;
    #pragma unroll
    for (int i = 0; i < 4; ++i){
      int r = rr + i*8;
      t[r][c] = w[(size_t)(k0 + r) * N + n0 + c];
    }
    __syncthreads();
    #pragma unroll
    for (int i = 0; i < 4; ++i){
      int r = rr + i*8;
      wT[(size_t)(n0 + r) * K + k0 + c] = f2bf(t[c][r]);
    }
  } else {
    int r = threadIdx.x >> 3, cc = (threadIdx.x & 7) * 8;
    #pragma unroll
    for (int tsel = 0; tsel < 2; ++tsel){
      const float* src = tsel ? rpw : rph;
      u16* dst = tsel ? rpwb : rphb;
      short8 v;
      #pragma unroll
      for (int e = 0; e < 8; ++e)
        v[e] = (r < 27) ? (short)f2bf(src[(size_t)r * 64 + cc + e]) : (short)0;
      *(short8*)(dst + (size_t)r * 64 + cc) = v;
    }
  }
}

// ================= 256x256 8-phase GEMM (T2+T3+T4+T5) =================
// MEASURED-BEST schedule (R8/R12/R15: 116.3-116.7us QKV). Structure
// experiments all regressed: BK32-3bar 123.7 (R10), BK32-1sync 128.2 (R11),
// 9-slot ring L=7 136.1 (R14), L=9 broken (R13). K-LOOP IS FROZEN.
// Counted vmcnt(4) waits sit BEFORE the barrier preceding the dependent
// ds_reads (phase1 guards {A1,B1}(t); phase3 guards {A0,B0}(t+1)); loads
// never drain below 4 outstanding. launch_bounds(512,2): natural VGPR ~100,
// no spill (R9: (512,4) caps VGPR at 64, spills acc -> 5-10x regression).
// MFMA operand-swapped (C^T frags). MODE 0: merged QKV epilogue, runtime
// branch per 1024-aligned column third. MODE 1: f32 out + bias.
template<int MODE>
__global__ __launch_bounds__(512, 2) void k_g256(const u16* __restrict__ Ab,
    const u16* __restrict__ Bt, const float* __restrict__ bias,
    u16* __restrict__ qg, u16* __restrict__ kg, u16* __restrict__ vTg,
    float* __restrict__ outf, int K, int N, int ntm, int ntn)
{
  extern __shared__ __align__(16) u16 smem[];   // [d][ab][ks][256][32] = 128 KiB
  const int tid = threadIdx.x;
  const int lane = tid & 63, wv = tid >> 6;
  const int wr = wv >> 2, wc = wv & 3;
  const int l16 = lane & 15, lk = lane >> 4;

  const int nwg = ntm * ntn;
  int bid = blockIdx.x;
  int q8 = nwg >> 3, r8 = nwg & 7;
  int xcd = bid & 7, loc = bid >> 3;
  int wgid = (xcd < r8 ? xcd*(q8+1) : r8*(q8+1) + (xcd - r8)*q8) + loc;
  int gsz = 8 * ntn;
  int g = wgid / gsz, rem = wgid - g * gsz;
  int gm = ntm - g * 8; if (gm > 8) gm = 8;
  int ry = g * 8 + rem % gm;
  int cy = rem / gm;
  const size_t m0 = (size_t)ry * 256;
  const size_t n0 = (size_t)cy * 256;
  const int nk = K >> 6;

  auto off = [&](int d, int ab, int ks){ return ((d*2 + ab)*2 + ks) * 8192; };

  auto stageH = [&](int d, int ab, int ks, int tile){
    const u16* src = ab ? Bt : Ab;
    size_t rb = ab ? n0 : m0;
    int c = (lane & 3) ^ ((lane >> 3) & 3);     // inverse read-swizzle on source
    #pragma unroll
    for (int i = 0; i < 2; ++i){
      int rh = 32*wv + 16*i + (lane >> 2);
      gload_lds16(src + (rb + rh) * (size_t)K + tile*64 + ks*32 + c*8,
                  smem + off(d, ab, ks) + (32*wv + 16*i) * 32);
    }
  };
  auto ldA = [&](short8* a, int d, int ks, int h){
    #pragma unroll
    for (int m2 = 0; m2 < 4; ++m2){
      int r = wr*128 + h*64 + m2*16 + l16;
      a[m2] = *(const short8*)(smem + off(d,0,ks) + r*32 + ((lk ^ ((r>>1)&3)) << 3));
    }
  };
  auto ldB = [&](short8* b, int d, int ks){
    #pragma unroll
    for (int ni = 0; ni < 4; ++ni){
      int r = wc*64 + ni*16 + l16;
      b[ni] = *(const short8*)(smem + off(d,1,ks) + r*32 + ((lk ^ ((r>>1)&3)) << 3));
    }
  };

  f32x4 acc[8][4] = {};
  auto mm = [&](int h, short8* a, short8* b){
    __builtin_amdgcn_s_setprio(1);
    #pragma unroll
    for (int m2 = 0; m2 < 4; ++m2)
      #pragma unroll
      for (int ni = 0; ni < 4; ++ni)
        acc[h*4+m2][ni] = __builtin_amdgcn_mfma_f32_16x16x32_bf16(b[ni], a[m2], acc[h*4+m2][ni], 0, 0, 0);
    __builtin_amdgcn_s_setprio(0);
  };

  // prologue: tile 0; guarantee {A0,B0}(0) before the loop's first ds_reads
  stageH(0, 0, 0, 0); stageH(0, 1, 0, 0); stageH(0, 0, 1, 0); stageH(0, 1, 1, 0);
  WAITV4(); BAR();

  #pragma unroll 1
  for (int kt = 0; kt < nk; ++kt){
    const int d = kt & 1, dn = d ^ 1;
    const int tn = (kt + 1 < nk) ? kt + 1 : nk - 1;  // redundant restage keeps wait counts valid
    short8 a[4], b0[4], b1[4];
    // phase 0: (h0, ks0) — {A0,B0}(kt) guaranteed by prev phase-3 wait + BAR
    ldA(a, d, 0, 0); ldB(b0, d, 0);
    stageH(dn, 0, 0, tn);
    BAR(); LGKM_FENCE();
    mm(0, a, b0);
    BAR();
    // phase 1: (h1, ks0) — reuse b0; wait completes {A1,B1}(kt) for phase 2
    ldA(a, d, 0, 1);
    stageH(dn, 1, 0, tn);
    WAITV4();
    BAR(); LGKM_FENCE();
    mm(1, a, b0);
    BAR();
    // phase 2: (h0, ks1)
    ldA(a, d, 1, 0); ldB(b1, d, 1);
    stageH(dn, 0, 1, tn);
    BAR(); LGKM_FENCE();
    mm(0, a, b1);
    BAR();
    // phase 3: (h1, ks1) — wait completes {A0,B0}(kt+1) for next phase 0
    ldA(a, d, 1, 1);
    stageH(dn, 1, 1, tn);
    WAITV4();
    BAR(); LGKM_FENCE();
    mm(1, a, b1);
    BAR();
  }

  const int rowb = (int)m0 + wr*128;
  const int colb = (int)n0 + wc*64;
  if constexpr (MODE == 1){
    #pragma unroll
    for (int mi = 0; mi < 8; ++mi){
      int r = rowb + mi*16 + l16;
      float* orow = outf + (size_t)r * N;
      #pragma unroll
      for (int ni = 0; ni < 4; ++ni){
        int c0 = colb + ni*16 + lk*4;
        f32x4 bz = *(const f32x4*)(bias + c0);
        f32x4 v = acc[mi][ni] + bz;
        *(f32x4*)(orow + c0) = v;
      }
    }
  } else {
    const int t3 = colb >> 10;
    if (t3 < 2){
      u16* dst0 = (t3 == 0) ? qg : kg;
      const float sc = (t3 == 0) ? 1.0f : 0.125f;   // fold qk-scale into K
      #pragma unroll
      for (int mi = 0; mi < 8; ++mi){
        int r = rowb + mi*16 + l16;
        int b = r / 196, n = r - b * 196;
        #pragma unroll
        for (int ni = 0; ni < 4; ++ni){
          int rr2 = ((colb & 1023) + ni*16);
          int hh = rr2 >> 6, ccb = (rr2 & 63) + lk*4;
          const float* bz = bias + colb + ni*16 + lk*4;
          u32 w0 = cvtpk_bf16((acc[mi][ni][0] + bz[0])*sc, (acc[mi][ni][1] + bz[1])*sc);
          u32 w1 = cvtpk_bf16((acc[mi][ni][2] + bz[2])*sc, (acc[mi][ni][3] + bz[3])*sc);
          u32* dst = (u32*)(dst0 + ((size_t)(hh*64 + b) * SP + n) * HD + ccb);
          dst[0] = w0; dst[1] = w1;
        }
      }
    } else {
      // v third (SW layout): per frag 4 scalar u16 stores, stride SPV elems.
      // Pads n in [196,224) are never written: attn multiplies them by P==0
      // exactly, and 0xAA / stale bf16 garbage is finite -> no memset needed.
      #pragma unroll
      for (int mi = 0; mi < 8; ++mi){
        int r = rowb + mi*16 + l16;
        int b = r / 196, n = r - b * 196;
        #pragma unroll
        for (int ni = 0; ni < 4; ++ni){
          int col0 = colb + ni*16 + lk*4;
          f32x4 bz = *(const f32x4*)(bias + col0);
          int rem2 = col0 & 1023;
          int hh = rem2 >> 6, cc0 = rem2 & 63;
          u16* base = vTg + ((size_t)(hh*64 + b) * HD + cc0) * SPV + n;
          #pragma unroll
          for (int i = 0; i < 4; ++i)
            base[(size_t)i * SPV] = f2bf(acc[mi][ni][i] + bz[i]);
        }
      }
    }
  }
}

// ---- fused attention: one BLOCK per bh (13 waves); K/V staged once in LDS ----
// R15-verified staging (simple cooperative loops). T14 async-STAGE variant
// REGRESSED (+16us, R16): 13-wave TLP already hides the staging latency;
// explicit reg-ILP only added register pressure. Do not re-apply.
#define KSTR 144
#define VSTR 464
#define PWB  7424
__global__ __launch_bounds__(832, 1) void k_attn(
    const u16* __restrict__ qg, const u16* __restrict__ kg, const u16* __restrict__ vTg,
    const u16* __restrict__ rphb, const u16* __restrict__ rpwb,
    u16* __restrict__ ao)
{
  extern __shared__ __align__(16) char asmem[];
  char* Klds = asmem;                    // 208 x 144B (128 used)
  char* Vlds = asmem + 29952;            // 64 x 464B (448 used)
  const int tid = threadIdx.x, lane = tid & 63, wvi = tid >> 6;  // 0..12
  const int l16 = lane & 15, lk = lane >> 4;
  char*  wbase = asmem + 59648 + wvi * PWB;
  float* relT  = (float*)wbase;          // [16][68] f32
  u32*   Pp    = (u32*)wbase;            // [16][116] u32 (alias; disjoint lifetime)

  const int bh = blockIdx.x;
  const int hh = bh >> 6, bb = bh & 63;
  const u16* qb = qg  + (size_t)bh * SP * HD;
  const u16* kb = kg  + (size_t)bh * SP * HD;
  const u16* vb = vTg + (size_t)bh * HD * SPV;

  for (int c = tid; c < 1664; c += 832){           // K: 208 rows x 8 chunks
    int row = c >> 3, colb = (c & 7) << 4;
    short8 d = *(const short8*)((const char*)kb + row*128 + colb);
    *(short8*)(Klds + row*KSTR + colb) = d;
  }
  for (int c = tid; c < 1792; c += 832){           // V: 64 rows x 28 chunks
    int row = c / 28, colb = (c - row*28) << 4;
    short8 d = *(const short8*)((const char*)vb + row*448 + colb);
    *(short8*)(Vlds + row*VSTR + colb) = d;
  }
  __syncthreads();

  const int mt = wvi;
  const short8 a0 = *(const short8*)(qb + (size_t)(mt*16 + l16) * HD + lk*8);
  const short8 a1 = *(const short8*)(qb + (size_t)(mt*16 + l16) * HD + 32 + lk*8);

  // rel tables via MFMA: lane(l16,lk) reg i = T[delta=dt*16+lk*4+i][q=l16]
  {
    f32x4 z = {0.f,0.f,0.f,0.f};
    f32x4 racc[2][2] = {{z,z},{z,z}};
    #pragma unroll
    for (int dt = 0; dt < 2; ++dt){
      short8 h0 = *(const short8*)(rphb + (size_t)(dt*16 + l16) * 64 + lk*8);
      short8 h1 = *(const short8*)(rphb + (size_t)(dt*16 + l16) * 64 + 32 + lk*8);
      short8 w0 = *(const short8*)(rpwb + (size_t)(dt*16 + l16) * 64 + lk*8);
      short8 w1 = *(const short8*)(rpwb + (size_t)(dt*16 + l16) * 64 + 32 + lk*8);
      racc[0][dt] = __builtin_amdgcn_mfma_f32_16x16x32_bf16(h0, a0, racc[0][dt], 0, 0, 0);
      racc[0][dt] = __builtin_amdgcn_mfma_f32_16x16x32_bf16(h1, a1, racc[0][dt], 0, 0, 0);
      racc[1][dt] = __builtin_amdgcn_mfma_f32_16x16x32_bf16(w0, a0, racc[1][dt], 0, 0, 0);
      racc[1][dt] = __builtin_amdgcn_mfma_f32_16x16x32_bf16(w1, a1, racc[1][dt], 0, 0, 0);
    }
    #pragma unroll
    for (int t = 0; t < 2; ++t)
      #pragma unroll
      for (int dt = 0; dt < 2; ++dt)
        *(f32x4*)(relT + l16*68 + t*32 + dt*16 + lk*4) = racc[t][dt];
  }
  DS_FENCE();

  int qr = mt*16 + l16;
  int qrc = qr > HW-1 ? HW-1 : qr;
  int qh = qrc / 14, qw = qrc - 14*qh;
  const float* rrow = relT + l16*68;
  const int dh0 = qh + 13, dw0 = 32 + qw + 13;
  const int lk4 = lk*4;

  f32x4 sacc[13];
  #pragma unroll
  for (int nt = 0; nt < 13; ++nt){
    #pragma unroll
    for (int i = 0; i < 4; ++i){
      int k = nt*16 + lk4 + i;
      int kh = (k * 4682) >> 16;
      if (nt == 12 && kh > 13) kh = 13;
      int kw = k - kh*14;
      float bias = rrow[dh0 - kh] + rrow[dw0 - kw];
      sacc[nt][i] = (nt == 12 && lk != 0) ? -1e30f : bias;
    }
  }

  #pragma unroll
  for (int nt = 0; nt < 13; ++nt){
    int row = nt*16 + l16;
    short8 b0 = *(const short8*)(Klds + row*KSTR + lk*16);
    short8 b1 = *(const short8*)(Klds + row*KSTR + 64 + lk*16);
    sacc[nt] = __builtin_amdgcn_mfma_f32_16x16x32_bf16(b0, a0, sacc[nt], 0, 0, 0);
    sacc[nt] = __builtin_amdgcn_mfma_f32_16x16x32_bf16(b1, a1, sacc[nt], 0, 0, 0);
  }

  float m;
  {
    float t0[13];
    #pragma unroll
    for (int nt = 0; nt < 13; ++nt)
      t0[nt] = fmaxf(fmaxf(sacc[nt][0], sacc[nt][1]), fmaxf(sacc[nt][2], sacc[nt][3]));
    float a01 = fmaxf(t0[0], t0[1]),  a23 = fmaxf(t0[2], t0[3]);
    float a45 = fmaxf(t0[4], t0[5]),  a67 = fmaxf(t0[6], t0[7]);
    float a89 = fmaxf(t0[8], t0[9]),  aab = fmaxf(t0[10], t0[11]);
    m = fmaxf(fmaxf(fmaxf(a01, a23), fmaxf(a45, a67)), fmaxf(fmaxf(a89, aab), t0[12]));
  }
  m = fmaxf(m, __shfl_xor(m, 16, 64));
  m = fmaxf(m, __shfl_xor(m, 32, 64));
  float sum;
  {
    float s4[13];
    #pragma unroll
    for (int nt = 0; nt < 13; ++nt){
      #pragma unroll
      for (int i = 0; i < 4; ++i)
        sacc[nt][i] = __expf(sacc[nt][i] - m);
      s4[nt] = (sacc[nt][0] + sacc[nt][1]) + (sacc[nt][2] + sacc[nt][3]);
    }
    float b01 = s4[0]+s4[1], b23 = s4[2]+s4[3], b45 = s4[4]+s4[5];
    float b67 = s4[6]+s4[7], b89 = s4[8]+s4[9], bab = s4[10]+s4[11];
    sum = ((b01+b23) + (b45+b67)) + ((b89+bab) + s4[12]);
  }
  sum += __shfl_xor(sum, 16, 64);
  sum += __shfl_xor(sum, 32, 64);
  float inv = 1.0f / sum;

  DS_FENCE();
  u32* prow = Pp + l16*116;
  #pragma unroll
  for (int nt = 0; nt < 13; ++nt){
    u32x2 wpk;
    wpk[0] = cvtpk_bf16(sacc[nt][0], sacc[nt][1]);
    wpk[1] = cvtpk_bf16(sacc[nt][2], sacc[nt][3]);
    *(u32x2*)(prow + nt*8 + lk*2) = wpk;
  }
  { u32x2 zz = {0u, 0u}; *(u32x2*)(prow + 104 + lk*2) = zz; }
  DS_FENCE();

  f32x4 z = {0.f,0.f,0.f,0.f};
  f32x4 oacc[4] = {z,z,z,z};
  #pragma unroll
  for (int kt = 0; kt < 7; ++kt){
    short8 pa = *(const short8*)(prow + kt*16 + lk4);
    #pragma unroll
    for (int dt = 0; dt < 4; ++dt){
      short8 bv = *(const short8*)(Vlds + (dt*16 + l16)*VSTR + kt*64 + lk*16);
      oacc[dt] = __builtin_amdgcn_mfma_f32_16x16x32_bf16(bv, pa, oacc[dt], 0, 0, 0);
    }
  }
  int qrow = mt*16 + l16;
  if (qrow < HW){
    u16* orow = ao + ((size_t)bb * HW + qrow) * DIM + hh * HD;
    #pragma unroll
    for (int dt = 0; dt < 4; ++dt){
      u32 lo = cvtpk_bf16(oacc[dt][0]*inv, oacc[dt][1]*inv);
      u32 hi = cvtpk_bf16(oacc[dt][2]*inv, oacc[dt][3]*inv);
      u32* dst = (u32*)(orow + dt*16 + lk4);
      dst[0] = lo; dst[1] = hi;
    }
  }
}

extern "C" void kernel_launch(void* const* d_in, const int* in_sizes, int n_in,
                              void* d_out, int out_size, void* d_ws, size_t ws_size,
                              hipStream_t stream)
{
  const float* x      = (const float*)d_in[0];
  const float* qkv_w  = (const float*)d_in[1];
  const float* qkv_b  = (const float*)d_in[2];
  const float* proj_w = (const float*)d_in[3];
  const float* proj_b = (const float*)d_in[4];
  const float* rph    = (const float*)d_in[5];
  const float* rpw    = (const float*)d_in[6];
  float* out = (float*)d_out;
  char* ws = (char*)d_ws;

  size_t off = 0;
  auto alloc = [&](size_t b){ size_t r = off; off += (b + 255) & ~(size_t)255; return r; };
  u16* wqkvT = (u16*)(ws + alloc((size_t)3072*1024*2));
  u16* wprojT= (u16*)(ws + alloc((size_t)1024*1024*2));
  u16* qg    = (u16*)(ws + alloc((size_t)NBH*SP*HD*2));
  u16* kg    = (u16*)(ws + alloc((size_t)NBH*SP*HD*2));
  u16* vTg   = (u16*)(ws + alloc((size_t)NBH*HD*SPV*2));
  u16* rphb  = (u16*)(ws + alloc((size_t)32*64*2));
  u16* rpwb  = (u16*)(ws + alloc((size_t)32*64*2));
  u16* xb    = (u16*)(ws + alloc((size_t)12544*1024*2));
  u16* ao    = xb;   // disjoint lifetimes

  hipFuncSetAttribute((const void*)k_g256<0>, hipFuncAttributeMaxDynamicSharedMemorySize, 131072);
  hipFuncSetAttribute((const void*)k_g256<1>, hipFuncAttributeMaxDynamicSharedMemorySize, 131072);
  hipFuncSetAttribute((const void*)k_attn,    hipFuncAttributeMaxDynamicSharedMemorySize, 156160);

  k_prep<<<10369, 256, 0, stream>>>(x, xb, qkv_w, wqkvT, proj_w, wprojT,
                                    rph, rpw, rphb, rpwb);
  k_g256<0><<<49*12, 512, 131072, stream>>>(xb, wqkvT, qkv_b, qg, kg, vTg, nullptr,
                                            1024, 3072, 49, 12);
  k_attn<<<1024, 832, 156160, stream>>>(qg, kg, vTg, rphb, rpwb, ao);
  k_g256<1><<<49*4, 512, 131072, stream>>>(ao, wprojT, proj_b, nullptr, nullptr, nullptr, out,
                                           1024, 1024, 49, 4);
}